// Round 1
// baseline (1055.149 us; speedup 1.0000x reference)
//
#include <hip/hip_runtime.h>
#include <hip/hip_bf16.h>

#define Bb 4
#define Ss 2048
#define Dm 1024
#define Hh 16
#define DKk 64
#define DVv 64

using short8  = __attribute__((ext_vector_type(8))) short;
using floatx4 = __attribute__((ext_vector_type(4))) float;

__device__ inline unsigned short f32_to_bf16(float f) {
    union { float f; unsigned int u; } x; x.f = f;
    unsigned int r = x.u + 0x7fffu + ((x.u >> 16) & 1u);
    return (unsigned short)(r >> 16);
}

// ---------------------------------------------------------------------------
// Weight transpose + cast: W (K=1024, N=1024) fp32 -> Wt (N, K) bf16
// ---------------------------------------------------------------------------
__global__ __launch_bounds__(256) void transpose_w(const float* __restrict__ W,
                                                   unsigned short* __restrict__ Wt) {
    __shared__ float tile[32][33];
    int n0 = blockIdx.x * 32, k0 = blockIdx.y * 32;
    int tx = threadIdx.x, ty = threadIdx.y;   // (32, 8)
    #pragma unroll
    for (int i = 0; i < 32; i += 8)
        tile[ty + i][tx] = W[(size_t)(k0 + ty + i) * Dm + n0 + tx];
    __syncthreads();
    #pragma unroll
    for (int i = 0; i < 32; i += 8)
        Wt[(size_t)(n0 + ty + i) * Dm + k0 + tx] = f32_to_bf16(tile[tx][ty + i]);
}

// ---------------------------------------------------------------------------
// Projection GEMM: A (8192 x 1024 fp32) @ Wt^T (+bias) -> bf16 out
// mode 0: out[((b*H+h)*S + s)*64 + d]   (Q, K layout)
// mode 1: out[((b*H+h)*64 + d)*S + s]   (V transposed layout)
// block 256 = 4 waves, block tile 64x128, wave tile 32x64
// ---------------------------------------------------------------------------
__global__ __launch_bounds__(256) void gemm_proj(const float* __restrict__ A,
                                                 const unsigned short* __restrict__ Bt,
                                                 const float* __restrict__ bias,
                                                 unsigned short* __restrict__ Out,
                                                 int mode) {
    const int wave = threadIdx.x >> 6;
    const int lane = threadIdx.x & 63;
    const int quad = lane >> 4;
    const int l16  = lane & 15;
    const int row_base = blockIdx.x * 64 + (wave & 1) * 32;
    const int col_base = blockIdx.y * 128 + (wave >> 1) * 64;

    floatx4 acc[2][4] = {};

    for (int k0 = 0; k0 < Dm; k0 += 32) {
        const int kk = k0 + quad * 8;
        short8 a[2], b[4];
        #pragma unroll
        for (int r = 0; r < 2; r++) {
            const floatx4* ap = (const floatx4*)(A + (size_t)(row_base + r * 16 + l16) * Dm + kk);
            floatx4 f0 = ap[0], f1 = ap[1];
            union { short8 v; unsigned short u[8]; } av;
            #pragma unroll
            for (int j = 0; j < 4; j++) {
                av.u[j]     = f32_to_bf16(f0[j]);
                av.u[4 + j] = f32_to_bf16(f1[j]);
            }
            a[r] = av.v;
        }
        #pragma unroll
        for (int c = 0; c < 4; c++)
            b[c] = *(const short8*)(Bt + (size_t)(col_base + c * 16 + l16) * Dm + kk);
        #pragma unroll
        for (int r = 0; r < 2; r++)
            #pragma unroll
            for (int c = 0; c < 4; c++)
                acc[r][c] = __builtin_amdgcn_mfma_f32_16x16x32_bf16(a[r], b[c], acc[r][c], 0, 0, 0);
    }

    #pragma unroll
    for (int r = 0; r < 2; r++)
        #pragma unroll
        for (int c = 0; c < 4; c++) {
            int n = col_base + c * 16 + l16;
            float bias_n = bias[n];
            int h = n >> 6, d = n & 63;
            #pragma unroll
            for (int i = 0; i < 4; i++) {
                int m = row_base + r * 16 + quad * 4 + i;
                unsigned short ob = f32_to_bf16(acc[r][c][i] + bias_n);
                int bb = m >> 11, s = m & (Ss - 1);
                if (mode == 0)
                    Out[((size_t)(bb * Hh + h) * Ss + s) * 64 + d] = ob;
                else
                    Out[((size_t)(bb * Hh + h) * 64 + d) * Ss + s] = ob;
            }
        }
}

// ---------------------------------------------------------------------------
// Flash attention: one block (4 waves) per (b, h, 64-row q-tile).
// Each wave owns 16 q rows; iterates 32-key tiles with online softmax.
// Qp/Kp: (B*H, S, 64) bf16; Vt: (B*H, 64, S) bf16; AO: (B, S, 1024) bf16
// ---------------------------------------------------------------------------
__global__ __launch_bounds__(256) void attn_kernel(const unsigned short* __restrict__ Qp,
                                                   const unsigned short* __restrict__ Kp,
                                                   const unsigned short* __restrict__ Vt,
                                                   const int* __restrict__ v_mask,
                                                   unsigned short* __restrict__ AO) {
    const int wave = threadIdx.x >> 6;
    const int lane = threadIdx.x & 63;
    const int quad = lane >> 4;
    const int l16  = lane & 15;
    const int qt = blockIdx.x;
    const int h  = blockIdx.y;
    const int b  = blockIdx.z;
    const int bh = b * Hh + h;
    const int qbase = qt * 64 + wave * 16;

    __shared__ __align__(16) unsigned short P_lds[4][16][32];

    // Q fragments (A-layout): row = l16, k = quad*8 + j (+32)
    const unsigned short* qptr = Qp + ((size_t)bh * Ss + qbase + l16) * 64 + quad * 8;
    short8 qf0 = *(const short8*)(qptr);
    short8 qf1 = *(const short8*)(qptr + 32);

    floatx4 o[4] = {};
    float mrow[4], lrow[4];
    #pragma unroll
    for (int i = 0; i < 4; i++) { mrow[i] = -3e38f; lrow[i] = 0.f; }

    const int ktEnd = qt * 64 + 64;
    for (int kt = 0; kt < ktEnd; kt += 32) {
        // K fragments (B-layout): col n = l16 (+16), k = quad*8 + j (+32)
        const unsigned short* kptr = Kp + ((size_t)bh * Ss + kt + l16) * 64 + quad * 8;
        short8 kf00 = *(const short8*)(kptr);
        short8 kf01 = *(const short8*)(kptr + 32);
        short8 kf10 = *(const short8*)(kptr + 16 * 64);
        short8 kf11 = *(const short8*)(kptr + 16 * 64 + 32);

        floatx4 s0 = {}, s1 = {};
        s0 = __builtin_amdgcn_mfma_f32_16x16x32_bf16(qf0, kf00, s0, 0, 0, 0);
        s0 = __builtin_amdgcn_mfma_f32_16x16x32_bf16(qf1, kf01, s0, 0, 0, 0);
        s1 = __builtin_amdgcn_mfma_f32_16x16x32_bf16(qf0, kf10, s1, 0, 0, 0);
        s1 = __builtin_amdgcn_mfma_f32_16x16x32_bf16(qf1, kf11, s1, 0, 0, 0);

        const int c0 = kt + l16, c1 = c0 + 16;
        float pen0 = (1.f - (float)v_mask[b * Ss + c0]) * 1e12f;
        float pen1 = (1.f - (float)v_mask[b * Ss + c1]) * 1e12f;

        float sv0[4], sv1[4];
        #pragma unroll
        for (int i = 0; i < 4; i++) {
            int r = qbase + quad * 4 + i;
            sv0[i] = s0[i] * 0.125f - pen0 - (c0 > r ? 1e12f : 0.f);
            sv1[i] = s1[i] * 0.125f - pen1 - (c1 > r ? 1e12f : 0.f);
        }

        float alpha[4];
        unsigned short pu0[4], pu1[4];
        #pragma unroll
        for (int i = 0; i < 4; i++) {
            float mx = fmaxf(sv0[i], sv1[i]);
            #pragma unroll
            for (int off = 1; off < 16; off <<= 1)
                mx = fmaxf(mx, __shfl_xor(mx, off, 64));
            float mnew = fmaxf(mrow[i], mx);
            alpha[i] = __expf(mrow[i] - mnew);
            float p0 = __expf(sv0[i] - mnew);
            float p1 = __expf(sv1[i] - mnew);
            float ps = p0 + p1;
            #pragma unroll
            for (int off = 1; off < 16; off <<= 1)
                ps += __shfl_xor(ps, off, 64);
            lrow[i] = lrow[i] * alpha[i] + ps;
            mrow[i] = mnew;
            pu0[i] = f32_to_bf16(p0);
            pu1[i] = f32_to_bf16(p1);
        }

        #pragma unroll
        for (int f = 0; f < 4; f++)
            #pragma unroll
            for (int i = 0; i < 4; i++)
                o[f][i] *= alpha[i];

        // P: C-layout -> A-layout via LDS (uniform trip count => barriers legal)
        __syncthreads();
        #pragma unroll
        for (int i = 0; i < 4; i++) {
            P_lds[wave][quad * 4 + i][l16]      = pu0[i];
            P_lds[wave][quad * 4 + i][l16 + 16] = pu1[i];
        }
        __syncthreads();
        short8 pf = *(const short8*)(&P_lds[wave][l16][quad * 8]);

        // V fragments (B-layout): n = d = f*16 + l16, k = quad*8 + j
        const unsigned short* vptr = Vt + ((size_t)bh * 64 + l16) * Ss + kt + quad * 8;
        #pragma unroll
        for (int f = 0; f < 4; f++) {
            short8 vf = *(const short8*)(vptr + (size_t)f * 16 * Ss);
            o[f] = __builtin_amdgcn_mfma_f32_16x16x32_bf16(pf, vf, o[f], 0, 0, 0);
        }
    }

    // epilogue: divide by row sums, write (B, S, H*64) bf16
    #pragma unroll
    for (int f = 0; f < 4; f++) {
        int d = h * 64 + f * 16 + l16;
        #pragma unroll
        for (int i = 0; i < 4; i++) {
            float val = o[f][i] / lrow[i];
            AO[((size_t)b * Ss + qbase + quad * 4 + i) * (Hh * DVv) + d] = f32_to_bf16(val);
        }
    }
}

// ---------------------------------------------------------------------------
// Output GEMM: AO (8192 x 1024 bf16) @ Wot^T + bo, * q_mask -> fp32 d_out
// ---------------------------------------------------------------------------
__global__ __launch_bounds__(256) void gemm_final(const unsigned short* __restrict__ A,
                                                  const unsigned short* __restrict__ Bt,
                                                  const float* __restrict__ bias,
                                                  const int* __restrict__ q_mask,
                                                  float* __restrict__ Out) {
    const int wave = threadIdx.x >> 6;
    const int lane = threadIdx.x & 63;
    const int quad = lane >> 4;
    const int l16  = lane & 15;
    const int row_base = blockIdx.x * 64 + (wave & 1) * 32;
    const int col_base = blockIdx.y * 128 + (wave >> 1) * 64;

    floatx4 acc[2][4] = {};

    for (int k0 = 0; k0 < Dm; k0 += 32) {
        const int kk = k0 + quad * 8;
        short8 a[2], b[4];
        #pragma unroll
        for (int r = 0; r < 2; r++)
            a[r] = *(const short8*)(A + (size_t)(row_base + r * 16 + l16) * Dm + kk);
        #pragma unroll
        for (int c = 0; c < 4; c++)
            b[c] = *(const short8*)(Bt + (size_t)(col_base + c * 16 + l16) * Dm + kk);
        #pragma unroll
        for (int r = 0; r < 2; r++)
            #pragma unroll
            for (int c = 0; c < 4; c++)
                acc[r][c] = __builtin_amdgcn_mfma_f32_16x16x32_bf16(a[r], b[c], acc[r][c], 0, 0, 0);
    }

    #pragma unroll
    for (int r = 0; r < 2; r++)
        #pragma unroll
        for (int c = 0; c < 4; c++) {
            int n = col_base + c * 16 + l16;
            float bias_n = bias[n];
            #pragma unroll
            for (int i = 0; i < 4; i++) {
                int m = row_base + r * 16 + quad * 4 + i;
                float qm = (float)q_mask[m];
                Out[(size_t)m * Dm + n] = (acc[r][c][i] + bias_n) * qm;
            }
        }
}

// ---------------------------------------------------------------------------
extern "C" void kernel_launch(void* const* d_in, const int* in_sizes, int n_in,
                              void* d_out, int out_size, void* d_ws, size_t ws_size,
                              hipStream_t stream) {
    const float* q      = (const float*)d_in[0];
    const float* k      = (const float*)d_in[1];
    const float* v      = (const float*)d_in[2];
    const int*   q_mask = (const int*)d_in[3];
    const int*   v_mask = (const int*)d_in[4];
    const float* Wq     = (const float*)d_in[5];
    const float* bq     = (const float*)d_in[6];
    const float* Wk     = (const float*)d_in[7];
    const float* bk     = (const float*)d_in[8];
    const float* Wv     = (const float*)d_in[9];
    const float* bv     = (const float*)d_in[10];
    const float* Wo     = (const float*)d_in[11];
    const float* bo     = (const float*)d_in[12];
    float* out = (float*)d_out;

    char* ws = (char*)d_ws;
    const size_t WT_SZ = (size_t)Dm * Dm * 2;                 // 2 MB each
    const size_t QP_SZ = (size_t)Bb * Hh * Ss * 64 * 2;       // 16 MB each
    unsigned short* Wtq = (unsigned short*)(ws);
    unsigned short* Wtk = (unsigned short*)(ws + WT_SZ);
    unsigned short* Wtv = (unsigned short*)(ws + 2 * WT_SZ);
    unsigned short* Wto = (unsigned short*)(ws + 3 * WT_SZ);
    unsigned short* Qp  = (unsigned short*)(ws + 4 * WT_SZ);
    unsigned short* Kp  = (unsigned short*)(ws + 4 * WT_SZ + QP_SZ);
    unsigned short* Vt  = (unsigned short*)(ws + 4 * WT_SZ + 2 * QP_SZ);
    unsigned short* AO  = (unsigned short*)(ws + 4 * WT_SZ + 3 * QP_SZ);

    dim3 tb(32, 8);
    dim3 tg(Dm / 32, Dm / 32);
    hipLaunchKernelGGL(transpose_w, tg, tb, 0, stream, Wq, Wtq);
    hipLaunchKernelGGL(transpose_w, tg, tb, 0, stream, Wk, Wtk);
    hipLaunchKernelGGL(transpose_w, tg, tb, 0, stream, Wv, Wtv);
    hipLaunchKernelGGL(transpose_w, tg, tb, 0, stream, Wo, Wto);

    const int M = Bb * Ss;  // 8192
    dim3 pg(M / 64, Dm / 128);
    hipLaunchKernelGGL(gemm_proj, pg, dim3(256), 0, stream, q, Wtq, bq, Qp, 0);
    hipLaunchKernelGGL(gemm_proj, pg, dim3(256), 0, stream, k, Wtk, bk, Kp, 0);
    hipLaunchKernelGGL(gemm_proj, pg, dim3(256), 0, stream, v, Wtv, bv, Vt, 1);

    dim3 ag(Ss / 64, Hh, Bb);
    hipLaunchKernelGGL(attn_kernel, ag, dim3(256), 0, stream, Qp, Kp, Vt, v_mask, AO);

    dim3 fg(M / 64, Dm / 128);
    hipLaunchKernelGGL(gemm_final, fg, dim3(256), 0, stream, AO, Wto, bo, q_mask, out);
}